// Round 13
// baseline (351.435 us; speedup 1.0000x reference)
//
#include <hip/hip_runtime.h>
#include <math.h>

// STC loss forward on MI355X — Round 13: cross-chunk software pipeline.
//
// R12 post-mortem: 245 us scan (~294 cy/step). Chain ~50 + issue ~50; rest is
// memory exposure: per-chunk ds_reads consumed immediately after the vmcnt
// drain (lgkm wait on first STEP), drain waits on DMA issued <1 chunk ago.
// Fix: 2-deep pipeline. Registers for chunk c staged during chunk c-1's
// compute; DMA for chunk c+2 issued while computing c; s_waitcnt vmcnt(9)
// waits only for the chunk issued one full chunk earlier. ds_reads get a
// whole chunk (~500 cy VALU) to land -> lgkm ~ free; DMA gets ~2 chunks.
//   loop (unroll x2): [issue DMA c+2] [vmcnt(9)] [stage c+1 -> other set]
//                     [clobber pin] [10 STEPs chunk c]
// 4 LDS buffers (k&3), CHUNK=10 (small named sets, ~50 VGPR each, no spill).
// Emit: 4 waves/block -> 16000 blocks (launch overhead ~4x down).
//
// STEP math unchanged (absmax 0.0 since R9): per column (P = O of col-1):
//   m = max(A,P); lz = log1p(exp(-|A-P|))
//   A' = m + lz + lq;   O' = (sk ? m+lz : A) + tok
// ACCEPT = LSE2(O1@lane49, A0@lane50).
// ws: tabA 51,200,000 B + tabB 256,000 B (+DMA overread ~8KB into slack;
// harness ws >= 51.7MB proven since R2).

#define T_LEN   2000
#define BATCH   32
#define NCLS    128
#define LTGT    100
#define CHUNK   10
#define NCHUNK  200          // T_LEN / CHUNK (even: loop unrolls x2)
#define XFERS   8            // 8 KiB >= 10*800 B per chunk
#define NEG_INF_F (-1e30f)

// ---------------------------------------------------------------- K1: emissions
// tabA[(b*T+t)*50 + j] = (tok_2j, tok_2j+1, lq_2j, lq_2j+1)
// tabB[b*T+t] = lq_100 = log(p_blank + wt*s)
__global__ void __launch_bounds__(256)
stc_emit(const float* __restrict__ inputs,   // (T,B,C) log-softmax
         const int*   __restrict__ targets,  // (B,L)
         float4*      __restrict__ tabA,
         float*       __restrict__ tabB,
         const float wt)
{
    const int tid  = threadIdx.x;
    const int lane = tid & 63;
    const int w    = tid >> 6;           // wave w owns row t = bx*4 + w
    const int t    = blockIdx.x * 4 + w;
    const int b    = blockIdx.y;

    __shared__ float lps[4][NCLS];

    const size_t base = ((size_t)t * BATCH + b) * NCLS;
    const float2 x = *(const float2*)(inputs + base + 2 * lane);
    *(float2*)&lps[w][2 * lane] = x;     // same-wave DS: in-order, no barrier

    const float ex = __expf(x.x), ey = __expf(x.y);
    float ps = (lane == 0) ? ey : (ex + ey);   // s excludes blank (class 0)
    #pragma unroll
    for (int off = 32; off >= 1; off >>= 1)
        ps += __shfl_xor(ps, off, 64);
    const float pb = __shfl(ex, 0, 64);  // blank prob

    if (lane < 50) {
        const int t0 = targets[b * LTGT + 2 * lane];
        const int t1 = targets[b * LTGT + 2 * lane + 1];
        const float lt0 = lps[w][t0], lt1 = lps[w][t1];
        const float aa  = fmaf(wt * (1.0f + 1e-7f), ps, pb);
        const float q0  = fmaf(-wt, __expf(lt0), aa);
        const float q1  = fmaf(-wt, __expf(lt1), aa);
        tabA[((size_t)b * T_LEN + t) * 50 + lane] =
            make_float4(lt0, lt1, __logf(q0), __logf(q1));
    } else if (lane == 50) {
        tabB[(size_t)b * T_LEN + t] = __logf(fmaf(wt, ps, pb));
    }
}

// ---------------------------------------------------------------- async DMA
__device__ __forceinline__ void async16(void* lds, const void* g)
{
    __builtin_amdgcn_global_load_lds(
        (const __attribute__((address_space(1))) unsigned int*)g,
        (__attribute__((address_space(3))) unsigned int*)lds, 16, 0, 0);
}
__device__ __forceinline__ void async4(void* lds, const void* g)
{
    __builtin_amdgcn_global_load_lds(
        (const __attribute__((address_space(1))) unsigned int*)g,
        (__attribute__((address_space(3))) unsigned int*)lds, 4, 0, 0);
}

// lane i <- lane i-1 across the wave64: DPP wave_shr:1, one VALU op.
__device__ __forceinline__ float shift_up1(float x)
{
    return __int_as_float(
        __builtin_amdgcn_update_dpp(0, __float_as_int(x),
                                    0x138, 0xf, 0xf, true));
}

// ---------------------------------------------------------------- K2: scan
__global__ void __launch_bounds__(64)
stc_scan(const float4* __restrict__ tabA,
         const float*  __restrict__ tabB,
         const int*    __restrict__ targets,
         float*        __restrict__ out)
{
    const int b    = blockIdx.x;
    const int lane = threadIdx.x;            // lane j owns cols 2j, 2j+1
    const bool l50 = (lane == 50);

    __shared__ float4 bufA[4][XFERS * 64];   // 4 x 8,192 B
    __shared__ float  bufB[4][64];           // 4 x 256 B

    // skip gates (per-lane constants)
    const int tb0 = b * LTGT;
    const int c0 = 2 * lane, c1 = 2 * lane + 1;
    bool skb0 = false, skb1 = false;
    if (c0 >= 1 && c0 <= 99)
        skb0 = (targets[tb0 + c0] != targets[tb0 + c0 - 1]);
    if (c1 <= 99)
        skb1 = (targets[tb0 + c1] != targets[tb0 + c1 - 1]);

    // merged log state: A = log(e^E + e^S); init alpha0 = {state0: 1}
    float A0 = (lane == 0) ? 0.0f : NEG_INF_F;
    float O0 = NEG_INF_F, A1 = NEG_INF_F, O1 = NEG_INF_F;
    float p0 = NEG_INF_F;

    const char*  gAbase = (const char*)tabA + (size_t)b * T_LEN * 800;
    const float* gBbase = tabB + (size_t)b * T_LEN;

#define ISSUE(k) do {                                                       \
        const char*  gA_ = gAbase + (size_t)(k) * (CHUNK * 800);            \
        const float* gB_ = gBbase + (k) * CHUNK;                            \
        char* dA_ = (char*)&bufA[(k) & 3][0];                               \
        _Pragma("unroll")                                                   \
        for (int i_ = 0; i_ < XFERS; ++i_)                                  \
            async16(dA_ + i_ * 1024,                                        \
                    gA_ + (size_t)i_ * 1024 + (size_t)lane * 16);           \
        async4(&bufB[(k) & 3][0], gB_ + lane);                              \
    } while (0)

#define DECLSET(p)                                                          \
    float4 p##v0,p##v1,p##v2,p##v3,p##v4,p##v5,p##v6,p##v7,p##v8,p##v9;     \
    float  p##q0,p##q1,p##q2,p##q3,p##q4,p##q5,p##q6,p##q7,p##q8,p##q9;

#define STAGESET(p, k) do {                                                 \
        const float4* lA_ = &bufA[(k) & 3][0];                              \
        const float*  lB_ = &bufB[(k) & 3][0];                              \
        p##v0=lA_[0*50+lane]; p##v1=lA_[1*50+lane]; p##v2=lA_[2*50+lane];   \
        p##v3=lA_[3*50+lane]; p##v4=lA_[4*50+lane]; p##v5=lA_[5*50+lane];   \
        p##v6=lA_[6*50+lane]; p##v7=lA_[7*50+lane]; p##v8=lA_[8*50+lane];   \
        p##v9=lA_[9*50+lane];                                               \
        p##q0=lB_[0]; p##q1=lB_[1]; p##q2=lB_[2]; p##q3=lB_[3];             \
        p##q4=lB_[4]; p##q5=lB_[5]; p##q6=lB_[6]; p##q7=lB_[7];             \
        p##q8=lB_[8]; p##q9=lB_[9];                                         \
    } while (0)

#define STEP(v, bq) do {                                                    \
        const float m1  = fmaxf(A1, O0);                                    \
        const float e1  = __expf(-fabsf(A1 - O0));                          \
        const float lz1 = __logf(1.0f + e1);                                \
        const float ml1 = m1 + lz1;                                         \
        const float O1n = (skb1 ? ml1 : A1) + (v).y;                        \
        const float psh = shift_up1(O1n);                                   \
        A1 = ml1 + (v).w;                                                   \
        O1 = O1n;                                                           \
        const float m0  = fmaxf(A0, p0);                                    \
        const float e0  = __expf(-fabsf(A0 - p0));                          \
        const float lz0 = __logf(1.0f + e0);                                \
        const float ml0 = m0 + lz0;                                         \
        const float lq0s = l50 ? (bq) : (v).z;                              \
        O0 = (skb0 ? ml0 : A0) + (v).x;                                     \
        A0 = ml0 + lq0s;                                                    \
        p0 = (lane == 0) ? NEG_INF_F : psh;                                 \
    } while (0)

#define RUNSET(p) do {                                                      \
        STEP(p##v0,p##q0); STEP(p##v1,p##q1); STEP(p##v2,p##q2);            \
        STEP(p##v3,p##q3); STEP(p##v4,p##q4); STEP(p##v5,p##q5);            \
        STEP(p##v6,p##q6); STEP(p##v7,p##q7); STEP(p##v8,p##q8);            \
        STEP(p##v9,p##q9);                                                  \
    } while (0)

    DECLSET(a)
    DECLSET(b)

    // prologue: chunks 0,1 in flight; stage chunk 0
    ISSUE(0);
    ISSUE(1);
    asm volatile("s_waitcnt vmcnt(9)" ::: "memory");   // chunk 0 landed
    STAGESET(a, 0);
    asm volatile("" ::: "memory");

    for (int c = 0; c < NCHUNK; c += 2) {
        // ---- phase 0: compute chunk c (set a); stage chunk c+1 (set b)
        if (c + 2 < NCHUNK) {
            ISSUE(c + 2);
            asm volatile("s_waitcnt vmcnt(9)" ::: "memory");  // c+1 landed
        } else {
            asm volatile("s_waitcnt vmcnt(0)" ::: "memory");
        }
        STAGESET(b, c + 1);
        asm volatile("" ::: "memory");
        RUNSET(a);
        // ---- phase 1: compute chunk c+1 (set b); stage chunk c+2 (set a)
        if (c + 3 < NCHUNK) {
            ISSUE(c + 3);
            asm volatile("s_waitcnt vmcnt(9)" ::: "memory");  // c+2 landed
        } else {
            asm volatile("s_waitcnt vmcnt(0)" ::: "memory");
        }
        if (c + 2 < NCHUNK) {
            STAGESET(a, c + 2);
        }
        asm volatile("" ::: "memory");
        RUNSET(b);
    }
#undef RUNSET
#undef STEP
#undef STAGESET
#undef DECLSET
#undef ISSUE

    // ACCEPT: LSE(O_99, E_100, S_100) = LSE2(O1@49, A0@50)
    const float vO = __shfl(O1, 49, 64);
    const float vA = __shfl(A0, 50, 64);
    if (lane == 0) {
        const float m  = fmaxf(vO, vA);
        const float lz = __logf(1.0f + __expf(-fabsf(vO - vA)));
        atomicAdd(out, -(m + lz) / ((float)T_LEN * (float)BATCH));
    }
}

// ---------------------------------------------------------------- launch
extern "C" void kernel_launch(void* const* d_in, const int* in_sizes, int n_in,
                              void* d_out, int out_size, void* d_ws, size_t ws_size,
                              hipStream_t stream)
{
    const float* inputs  = (const float*)d_in[0];   // (2000,32,128) f32
    const int*   targets = (const int*)d_in[1];     // (32,100) i32
    float*       out     = (float*)d_out;           // scalar f32

    float4* tabA = (float4*)d_ws;                                   // 51.2 MB
    float*  tabB = (float*)((char*)d_ws + (size_t)BATCH * T_LEN * 50 * 16);

    // wt = WLAST + (W0-WLAST)*exp(-NSTEP*ln2/THALF)
    const float wt = (float)(0.1 + 0.9 * exp(-log(2.0) / 10000.0));

    (void)hipMemsetAsync(out, 0, sizeof(float), stream);
    stc_emit<<<dim3(T_LEN / 4, BATCH), dim3(256), 0, stream>>>(inputs, targets,
                                                               tabA, tabB, wt);
    stc_scan<<<dim3(BATCH), dim3(64), 0, stream>>>(tabA, tabB, targets, out);
}